// Round 1
// baseline (1083.861 us; speedup 1.0000x reference)
//
#include <hip/hip_runtime.h>

#define Bsz   32
#define Hh    8
#define Ww    128
#define Cc    512
#define NHEAD 8
#define HD    64
#define NN    1024           // Hh*Ww
#define SCALE 0.125f         // 64^-0.5
#define ROWS  1536           // 3*Cc, qkv row stride

// ---------------------------------------------------------------------------
// Tiled fp32 GEMM: C[M,Nn] = A[M,K] (row stride lda) * B[K,Nn] (+ bias)
// 128x128 tile, BK=32, 256 threads, 8x8 per thread. A staged transposed in
// LDS so the inner loop is pure float4 reads.
// ---------------------------------------------------------------------------
template<bool HAS_BIAS>
__global__ __launch_bounds__(256) void gemm128(
    const float* __restrict__ A, int lda,
    const float* __restrict__ Bm,
    const float* __restrict__ bias,
    float* __restrict__ Cm,
    int M, int Nn, int K)
{
  constexpr int BM = 128, BN = 128, BK = 32;
  __shared__ float As[BK][BM + 4];   // transposed: As[k][m]; stride 132 (16B-aligned rows)
  __shared__ float Bs[BK][BN + 4];

  const int t  = threadIdx.x;
  const int bm = blockIdx.y * BM;
  const int bn = blockIdx.x * BN;
  const int tx = t & 15;             // col group -> cols tx*8..+7
  const int ty = t >> 4;             // row group -> rows ty*8..+7

  float acc[8][8] = {};

  // staging coords
  const int am  = t >> 3;            // 0..31 (A row within tile, +32 per iter)
  const int ak  = (t & 7) << 2;      // 0,4,..,28 (A k within tile)
  const int bk  = t >> 5;            // 0..7  (B k within tile, +8 per iter)
  const int bn4 = (t & 31) << 2;     // 0..124 (B col within tile)

  for (int k0 = 0; k0 < K; k0 += BK) {
#pragma unroll
    for (int r = 0; r < 4; ++r) {
      const int m = am + 32 * r;
      const float4 av = *reinterpret_cast<const float4*>(
          &A[(size_t)(bm + m) * lda + k0 + ak]);
      As[ak + 0][m] = av.x; As[ak + 1][m] = av.y;
      As[ak + 2][m] = av.z; As[ak + 3][m] = av.w;
    }
#pragma unroll
    for (int r = 0; r < 4; ++r) {
      const int kk = bk + 8 * r;
      *reinterpret_cast<float4*>(&Bs[kk][bn4]) =
          *reinterpret_cast<const float4*>(&Bm[(size_t)(k0 + kk) * Nn + bn + bn4]);
    }
    __syncthreads();

    for (int kk = 0; kk < BK; ++kk) {
      float a[8], bb[8];
      *reinterpret_cast<float4*>(&a[0]) = *reinterpret_cast<const float4*>(&As[kk][ty * 8]);
      *reinterpret_cast<float4*>(&a[4]) = *reinterpret_cast<const float4*>(&As[kk][ty * 8 + 4]);
      *reinterpret_cast<float4*>(&bb[0]) = *reinterpret_cast<const float4*>(&Bs[kk][tx * 8]);
      *reinterpret_cast<float4*>(&bb[4]) = *reinterpret_cast<const float4*>(&Bs[kk][tx * 8 + 4]);
#pragma unroll
      for (int i = 0; i < 8; ++i)
#pragma unroll
        for (int j = 0; j < 8; ++j)
          acc[i][j] += a[i] * bb[j];
    }
    __syncthreads();
  }

#pragma unroll
  for (int i = 0; i < 8; ++i) {
    const size_t row = (size_t)(bm + ty * 8 + i);
#pragma unroll
    for (int j = 0; j < 8; j += 4) {
      float4 v;
      v.x = acc[i][j + 0]; v.y = acc[i][j + 1];
      v.z = acc[i][j + 2]; v.w = acc[i][j + 3];
      if (HAS_BIAS) {
        v.x += bias[bn + tx * 8 + j + 0];
        v.y += bias[bn + tx * 8 + j + 1];
        v.z += bias[bn + tx * 8 + j + 2];
        v.w += bias[bn + tx * 8 + j + 3];
      }
      *reinterpret_cast<float4*>(&Cm[row * Nn + bn + tx * 8 + j]) = v;
    }
  }
}

// ---------------------------------------------------------------------------
// Local-window attention, flash-style over key rows.
// Block = 256 threads = 16 queries x 16 lane-groups, handles (b, head, h,
// 16-wide w-tile). Keys: rows h-3..h+3 (clipped), cols w0-5..w0+20 (clipped).
// Online softmax per query held in the 16-lane group's registers.
// Output written IN-PLACE into the q-columns of qkv (cols head*64..+63 of
// rows this block owns) -- each block writes exactly the q region only it
// reads, after its last read, so there is no cross-block race.
// ---------------------------------------------------------------------------
__global__ __launch_bounds__(256) void local_attn(float* __restrict__ qkv)
{
  const int wt   = blockIdx.x;        // 0..7
  const int head = blockIdx.y;        // 0..7
  const int h    = blockIdx.z & 7;    // 0..7
  const int b    = blockIdx.z >> 3;   // 0..31
  const int t    = threadIdx.x;
  const int w0   = wt * 16;

  __shared__ float Qs[16][68];
  __shared__ float Ks[26][68];
  __shared__ float Vs[26][68];
  __shared__ float Ps[16][32];

  const int q = t >> 4;   // query within tile (0..15)
  const int g = t & 15;   // lane group (0..15)

  // ---- stage Q (16 x 64 floats, one float4/thread) ----
  float* qkv_b = qkv + (size_t)b * NN * ROWS;
  {
    const int qq = t >> 4, d4 = (t & 15) << 2;
    const float4 v = *reinterpret_cast<const float4*>(
        &qkv_b[(size_t)(h * Ww + w0 + qq) * ROWS + head * HD + d4]);
    *reinterpret_cast<float4*>(&Qs[qq][d4]) = v;
  }

  const int r0 = max(0, h - 3), r1 = min(Hh - 1, h + 3);
  const int c0 = max(0, w0 - 5), c1 = min(Ww - 1, w0 + 15 + 5);
  const int cn = c1 - c0 + 1;          // 21 or 26
  const int w  = w0 + q;               // this group's query column

  float m_run = -1e30f, s_run = 0.f;
  float4 o = {0.f, 0.f, 0.f, 0.f};     // output slice d = g*4..g*4+3

  for (int kr = r0; kr <= r1; ++kr) {
    // ---- stage K,V rows (cn x 64 each, float4) ----
    const float* kbase = qkv_b + (size_t)(kr * Ww + c0) * ROWS + Cc + head * HD;
    const float* vbase = kbase + Cc;
    __syncthreads();                    // protect Ks/Vs from previous PV readers
    for (int i = t; i < cn * 16; i += 256) {
      const int c = i >> 4, d4 = (i & 15) << 2;
      *reinterpret_cast<float4*>(&Ks[c][d4]) =
          *reinterpret_cast<const float4*>(&kbase[(size_t)c * ROWS + d4]);
      *reinterpret_cast<float4*>(&Vs[c][d4]) =
          *reinterpret_cast<const float4*>(&vbase[(size_t)c * ROWS + d4]);
    }
    __syncthreads();

    // ---- scores for cols c=g and c=g+16 ----
    float sc0 = -1e30f, sc1 = -1e30f;
#pragma unroll 1
    for (int pass = 0; pass < 2; ++pass) {
      const int c = g + pass * 16;
      if (c < cn) {
        const int cg = c0 + c;
        if (cg >= w - 5 && cg <= w + 5) {
          float accd = 0.f;
#pragma unroll
          for (int d4 = 0; d4 < 16; ++d4) {
            const float4 qv = *reinterpret_cast<const float4*>(&Qs[q][d4 * 4]);
            const float4 kv = *reinterpret_cast<const float4*>(&Ks[c][d4 * 4]);
            accd += qv.x * kv.x + qv.y * kv.y + qv.z * kv.z + qv.w * kv.w;
          }
          if (pass == 0) sc0 = accd * SCALE; else sc1 = accd * SCALE;
        }
      }
    }

    // ---- online softmax across the 16-lane group ----
    float m_new = fmaxf(m_run, fmaxf(sc0, sc1));
#pragma unroll
    for (int msk = 1; msk < 16; msk <<= 1)
      m_new = fmaxf(m_new, __shfl_xor(m_new, msk));
    const float p0 = __expf(sc0 - m_new);
    const float p1 = __expf(sc1 - m_new);
    const float alpha = __expf(m_run - m_new);
    float psum = p0 + p1;
#pragma unroll
    for (int msk = 1; msk < 16; msk <<= 1)
      psum += __shfl_xor(psum, msk);
    s_run = s_run * alpha + psum;
    m_run = m_new;
    Ps[q][g] = p0;
    Ps[q][g + 16] = p1;
    __syncthreads();

    // ---- PV accumulate ----
    o.x *= alpha; o.y *= alpha; o.z *= alpha; o.w *= alpha;
    for (int c = 0; c < cn; ++c) {
      const float p = Ps[q][c];
      const float4 v = *reinterpret_cast<const float4*>(&Vs[c][g * 4]);
      o.x += p * v.x; o.y += p * v.y; o.z += p * v.z; o.w += p * v.w;
    }
  }

  // ---- normalize and write in-place into the q-columns ----
  const float inv = 1.0f / s_run;
  float4 res;
  res.x = o.x * inv; res.y = o.y * inv; res.z = o.z * inv; res.w = o.w * inv;
  __syncthreads();   // all reads of Q/K/V for this block are done
  *reinterpret_cast<float4*>(
      &qkv_b[(size_t)(h * Ww + w0 + q) * ROWS + head * HD + g * 4]) = res;
}

// ---------------------------------------------------------------------------
extern "C" void kernel_launch(void* const* d_in, const int* in_sizes, int n_in,
                              void* d_out, int out_size, void* d_ws, size_t ws_size,
                              hipStream_t stream)
{
  const float* x      = (const float*)d_in[0];   // [32, 1024, 512]
  const float* w_qkv  = (const float*)d_in[1];   // [512, 1536]
  const float* w_proj = (const float*)d_in[2];   // [512, 512]
  const float* b_proj = (const float*)d_in[3];   // [512]
  float* out = (float*)d_out;                    // [32, 1024, 512]
  float* qkv = (float*)d_ws;                     // [32768, 1536] fp32 = 201.3 MB

  const int M = Bsz * NN;                        // 32768

  // 1) qkv = x @ w_qkv
  gemm128<false><<<dim3(ROWS / 128, M / 128), 256, 0, stream>>>(
      x, Cc, w_qkv, nullptr, qkv, M, ROWS, Cc);

  // 2) local attention; attn output lands in qkv's q-columns
  local_attn<<<dim3(Ww / 16, NHEAD, Bsz * Hh), 256, 0, stream>>>(qkv);

  // 3) out = attn @ w_proj + b_proj   (A = q-columns of qkv, lda = 1536)
  gemm128<true><<<dim3(Cc / 128, M / 128), 256, 0, stream>>>(
      qkv, ROWS, w_proj, b_proj, out, M, Cc, Cc);
}

// Round 2
// 519.094 us; speedup vs baseline: 2.0880x; 2.0880x over previous
//
#include <hip/hip_runtime.h>

#define Bsz   32
#define Hh    8
#define Ww    128
#define Cc    512
#define NHEAD 8
#define HD    64
#define NN    1024
#define SCALE 0.125f
#define ROWS  1536

typedef _Float16 f16x8 __attribute__((ext_vector_type(8)));
typedef _Float16 h2    __attribute__((ext_vector_type(2)));
typedef float    f32x4 __attribute__((ext_vector_type(4)));

// ---------------------------------------------------------------------------
// async global->LDS, 16B per lane (linear layout only)
// ---------------------------------------------------------------------------
__device__ __forceinline__ void gload16(const _Float16* g, _Float16* l) {
#if __has_builtin(__builtin_amdgcn_global_load_lds)
  __builtin_amdgcn_global_load_lds(
      (const __attribute__((address_space(1))) unsigned int*)g,
      (__attribute__((address_space(3))) unsigned int*)l, 16, 0, 0);
#else
  *(uint4*)l = *(const uint4*)g;
#endif
}

// ---------------------------------------------------------------------------
// converts
// ---------------------------------------------------------------------------
__global__ __launch_bounds__(256) void cvt_f32_f16(
    const float* __restrict__ in, _Float16* __restrict__ out, int n4) {
  const int i = blockIdx.x * 256 + threadIdx.x;
  if (i < n4) {
    const float4 v = *reinterpret_cast<const float4*>(&in[(size_t)i * 4]);
    _Float16 h[4] = {(_Float16)v.x, (_Float16)v.y, (_Float16)v.z, (_Float16)v.w};
    *reinterpret_cast<uint2*>(&out[(size_t)i * 4]) = *reinterpret_cast<uint2*>(h);
  }
}

// out[n*K + k] = in[k*Nn + n]  (f32 -> f16 transpose)
__global__ __launch_bounds__(256) void tcvt(
    const float* __restrict__ in, _Float16* __restrict__ out, int Nn, int K) {
  const int id = blockIdx.x * 256 + threadIdx.x;
  if (id < Nn * K) {
    const int n = id / K, k = id - n * K;
    out[id] = (_Float16)in[(size_t)k * Nn + n];
  }
}

// ---------------------------------------------------------------------------
// MFMA GEMM: C[M,Nn] = A[M,K](f16) * BT[Nn,K]^T(f16)  (+bias), 128x128 tile,
// BK=32, 4 waves, 4x4 fragments of mfma_f32_16x16x32_f16 per wave.
// ---------------------------------------------------------------------------
template<bool OUT_F16, bool HAS_BIAS>
__global__ __launch_bounds__(256, 2) void gemm_mfma(
    const _Float16* __restrict__ A,
    const _Float16* __restrict__ BT,
    const float* __restrict__ bias,
    void* __restrict__ Cout,
    int Nn, int K)
{
  __shared__ _Float16 As[128 * 32];
  __shared__ _Float16 Bs[128 * 32];

  const int t  = threadIdx.x;
  const int bn = blockIdx.x * 128;
  const int bm = blockIdx.y * 128;
  const int l  = t & 63, wv = t >> 6;
  const int wr = wv >> 1, wc = wv & 1;

  f32x4 acc[4][4] = {};

  const int arow = t >> 2;            // 0..63
  const int ac   = (t & 3) * 8;       // k chunk start (halfs)

  for (int k0 = 0; k0 < K; k0 += 32) {
    __syncthreads();
    gload16(A  + (size_t)(bm + arow)      * K + k0 + ac, &As[t * 8]);
    gload16(A  + (size_t)(bm + 64 + arow) * K + k0 + ac, &As[2048 + t * 8]);
    gload16(BT + (size_t)(bn + arow)      * K + k0 + ac, &Bs[t * 8]);
    gload16(BT + (size_t)(bn + 64 + arow) * K + k0 + ac, &Bs[2048 + t * 8]);
    __syncthreads();

    const int rA = l & 15, ks = (l >> 4) * 8;
    f16x8 aF[4], bF[4];
#pragma unroll
    for (int i = 0; i < 4; ++i)
      aF[i] = *(const f16x8*)&As[(wr * 64 + i * 16 + rA) * 32 + ks];
#pragma unroll
    for (int j = 0; j < 4; ++j)
      bF[j] = *(const f16x8*)&Bs[(wc * 64 + j * 16 + rA) * 32 + ks];
#pragma unroll
    for (int i = 0; i < 4; ++i)
#pragma unroll
      for (int j = 0; j < 4; ++j)
        acc[i][j] = __builtin_amdgcn_mfma_f32_16x16x32_f16(aF[i], bF[j], acc[i][j], 0, 0, 0);
  }

  const int lc = l & 15, lr4 = (l >> 4) * 4;
#pragma unroll
  for (int i = 0; i < 4; ++i) {
    const int row0 = bm + wr * 64 + i * 16 + lr4;
#pragma unroll
    for (int j = 0; j < 4; ++j) {
      const int col = bn + wc * 64 + j * 16 + lc;
      const float bv = HAS_BIAS ? bias[col] : 0.f;
#pragma unroll
      for (int r = 0; r < 4; ++r) {
        const float v = acc[i][j][r] + bv;
        if (OUT_F16)
          ((_Float16*)Cout)[(size_t)(row0 + r) * Nn + col] = (_Float16)v;
        else
          ((float*)Cout)[(size_t)(row0 + r) * Nn + col] = v;
      }
    }
  }
}

// ---------------------------------------------------------------------------
// Local attention: block = (w-tile of 16) x (head) x (batch); stages ALL 8
// key rows (x <=26 cols) of K and V once in LDS (f16), then loops the 8 query
// rows h, reusing K/V 7x. 256 thr = 16 queries x 16 d-groups. fp32 math.
// ---------------------------------------------------------------------------
__device__ __forceinline__ float dotQK(const _Float16* qp, const _Float16* kp) {
  const h2* q2 = (const h2*)qp;
  const h2* k2 = (const h2*)kp;
  float acc = 0.f;
#pragma unroll
  for (int i = 0; i < 32; ++i) {
#if __has_builtin(__builtin_amdgcn_fdot2)
    acc = __builtin_amdgcn_fdot2(q2[i], k2[i], acc, false);
#else
    acc += (float)q2[i][0] * (float)k2[i][0] + (float)q2[i][1] * (float)k2[i][1];
#endif
  }
  return acc;
}

__global__ __launch_bounds__(256, 2) void local_attn_f16(
    const _Float16* __restrict__ qkv, _Float16* __restrict__ outh)
{
  const int wt = blockIdx.x, head = blockIdx.y, b = blockIdx.z;
  const int t  = threadIdx.x;
  const int w0 = wt * 16;
  const int c0 = max(0, w0 - 5);
  const int c1 = min(Ww - 1, w0 + 20);
  const int cn = c1 - c0 + 1;          // 21 or 26

  // c-stride 72 halfs = 144B: 16B-aligned, +4-bank advance -> conflict-free
  __shared__ _Float16 Ksh[8 * 26 * 72];
  __shared__ _Float16 Vsh[8 * 26 * 72];
  __shared__ _Float16 Qs[16 * 72];
  __shared__ float    Ps[16 * 26];

  const _Float16* qb = qkv + (size_t)b * NN * ROWS;

  // ---- stage all K,V rows (8 x cn x 64 halfs each) ----
  const int nchunk = 8 * cn * 8;       // 16B chunks
  for (int i = t; i < nchunk; i += 256) {
    const int kr  = i / (cn * 8);
    const int rem = i - kr * (cn * 8);
    const int c   = rem >> 3, d8 = (rem & 7) * 8;
    const size_t gofs = (size_t)(kr * Ww + c0 + c) * ROWS + head * HD + d8;
    *(uint4*)&Ksh[(kr * 26 + c) * 72 + d8] = *(const uint4*)&qb[gofs + Cc];
    *(uint4*)&Vsh[(kr * 26 + c) * 72 + d8] = *(const uint4*)&qb[gofs + 2 * Cc];
  }

  const int q = t >> 4, g = t & 15;
  const int w = w0 + q;

  for (int h = 0; h < Hh; ++h) {
    __syncthreads();                   // also covers initial K/V staging
    if (t < 128) {
      const int qq = t >> 3, d8 = (t & 7) * 8;
      *(uint4*)&Qs[qq * 72 + d8] =
          *(const uint4*)&qb[(size_t)(h * Ww + w0 + qq) * ROWS + head * HD + d8];
    }
    __syncthreads();

    const int r0 = max(0, h - 3), r1 = min(Hh - 1, h + 3);
    float m_run = -1e30f, s_run = 0.f;
    float4 o = {0.f, 0.f, 0.f, 0.f};

    for (int kr = r0; kr <= r1; ++kr) {
      float sc0 = -1e30f, sc1 = -1e30f;
      {
        const int cg = c0 + g;
        if (g < cn && cg >= w - 5 && cg <= w + 5)
          sc0 = dotQK(&Qs[q * 72], &Ksh[(kr * 26 + g) * 72]) * SCALE;
      }
      {
        const int c = g + 16, cg = c0 + c;
        if (c < cn && cg >= w - 5 && cg <= w + 5)
          sc1 = dotQK(&Qs[q * 72], &Ksh[(kr * 26 + c) * 72]) * SCALE;
      }

      float m_new = fmaxf(m_run, fmaxf(sc0, sc1));
#pragma unroll
      for (int msk = 1; msk < 16; msk <<= 1)
        m_new = fmaxf(m_new, __shfl_xor(m_new, msk));
      const float p0 = __expf(sc0 - m_new);
      const float p1 = __expf(sc1 - m_new);
      const float alpha = __expf(m_run - m_new);
      float psum = p0 + p1;
#pragma unroll
      for (int msk = 1; msk < 16; msk <<= 1)
        psum += __shfl_xor(psum, msk);
      s_run = s_run * alpha + psum;
      m_run = m_new;

      // Ps[q][*] written & read only by this q's own 16 lanes (same wave)
      Ps[q * 26 + g] = p0;
      if (g < 10) Ps[q * 26 + g + 16] = p1;

      o.x *= alpha; o.y *= alpha; o.z *= alpha; o.w *= alpha;
      for (int c = 0; c < cn; ++c) {
        const float p = Ps[q * 26 + c];
        const h2* vp = (const h2*)&Vsh[(kr * 26 + c) * 72 + g * 4];
        const h2 v01 = vp[0], v23 = vp[1];
        o.x += p * (float)v01[0]; o.y += p * (float)v01[1];
        o.z += p * (float)v23[0]; o.w += p * (float)v23[1];
      }
    }

    const float inv = 1.f / s_run;
    _Float16 r4[4] = {(_Float16)(o.x * inv), (_Float16)(o.y * inv),
                      (_Float16)(o.z * inv), (_Float16)(o.w * inv)};
    *(uint2*)&outh[((size_t)b * NN + h * Ww + w0 + q) * Cc + head * HD + g * 4] =
        *(uint2*)r4;
  }
}

// ---------------------------------------------------------------------------
extern "C" void kernel_launch(void* const* d_in, const int* in_sizes, int n_in,
                              void* d_out, int out_size, void* d_ws, size_t ws_size,
                              hipStream_t stream)
{
  const float* x      = (const float*)d_in[0];   // [32,1024,512]
  const float* w_qkv  = (const float*)d_in[1];   // [512,1536]
  const float* w_proj = (const float*)d_in[2];   // [512,512]
  const float* b_proj = (const float*)d_in[3];   // [512]
  float* out = (float*)d_out;

  const int M = Bsz * NN;                        // 32768
  char* ws = (char*)d_ws;
  _Float16* xh    = (_Float16*)ws;                              // 33.55 MB
  _Float16* qkvh  = (_Float16*)(ws + 33554432);                 // 100.66 MB
  _Float16* attnh = (_Float16*)(ws + 33554432 + 100663296);     // 33.55 MB
  _Float16* wqT   = (_Float16*)(ws + 167772160);                // 1.57 MB
  _Float16* wpT   = (_Float16*)(ws + 167772160 + 1572864);      // 0.52 MB

  // converts
  cvt_f32_f16<<<(M * Cc / 4 + 255) / 256, 256, 0, stream>>>(x, xh, M * Cc / 4);
  tcvt<<<(ROWS * Cc + 255) / 256, 256, 0, stream>>>(w_qkv, wqT, ROWS, Cc);
  tcvt<<<(Cc * Cc + 255) / 256, 256, 0, stream>>>(w_proj, wpT, Cc, Cc);

  // qkv = x @ w_qkv   (f16 out)
  gemm_mfma<true, false><<<dim3(ROWS / 128, M / 128), 256, 0, stream>>>(
      xh, wqT, nullptr, qkvh, ROWS, Cc);

  // local attention -> compact f16 [32768,512]
  local_attn_f16<<<dim3(Ww / 16, NHEAD, Bsz), 256, 0, stream>>>(qkvh, attnh);

  // out = attn @ w_proj + bias  (f32 out)
  gemm_mfma<false, true><<<dim3(Cc / 128, M / 128), 256, 0, stream>>>(
      attnh, wpT, b_proj, out, Cc, Cc);
}

// Round 3
// 239.371 us; speedup vs baseline: 4.5280x; 2.1686x over previous
//
#include <hip/hip_runtime.h>

#define Bsz   32
#define Hh    8
#define Ww    128
#define Cc    512
#define NHEAD 8
#define HD    64
#define NN    1024
#define SCALE 0.125f
#define ROWS  1536

typedef _Float16 f16x8 __attribute__((ext_vector_type(8)));
typedef float    f32x4 __attribute__((ext_vector_type(4)));

// ---------------------------------------------------------------------------
// async global->LDS, 16B per lane (linear dest = wave base + lane*16)
// ---------------------------------------------------------------------------
__device__ __forceinline__ void gload16(const _Float16* g, _Float16* l) {
#if __has_builtin(__builtin_amdgcn_global_load_lds)
  __builtin_amdgcn_global_load_lds(
      (const __attribute__((address_space(1))) unsigned int*)g,
      (__attribute__((address_space(3))) unsigned int*)l, 16, 0, 0);
#else
  *(uint4*)l = *(const uint4*)g;
#endif
}

// ---------------------------------------------------------------------------
// converts
// ---------------------------------------------------------------------------
__global__ __launch_bounds__(256) void cvt_f32_f16(
    const float* __restrict__ in, _Float16* __restrict__ out, int n4) {
  const int i = blockIdx.x * 256 + threadIdx.x;
  if (i < n4) {
    const float4 v = *reinterpret_cast<const float4*>(&in[(size_t)i * 4]);
    _Float16 h[4] = {(_Float16)v.x, (_Float16)v.y, (_Float16)v.z, (_Float16)v.w};
    *reinterpret_cast<uint2*>(&out[(size_t)i * 4]) = *reinterpret_cast<uint2*>(h);
  }
}

// out[n*K + k] = in[k*Nn + n]  (f32 -> f16 transpose)
__global__ __launch_bounds__(256) void tcvt(
    const float* __restrict__ in, _Float16* __restrict__ out, int Nn, int K) {
  const int id = blockIdx.x * 256 + threadIdx.x;
  if (id < Nn * K) {
    const int n = id / K, k = id - n * K;
    out[id] = (_Float16)in[(size_t)k * Nn + n];
  }
}

// ---------------------------------------------------------------------------
// MFMA GEMM: C[M,Nn] = A[M,K](f16) * BT[Nn,K]^T(f16)  (+bias), 128x128 tile,
// BK=32, 4 waves, 4x4 fragments of mfma_f32_16x16x32_f16 per wave.
// ---------------------------------------------------------------------------
template<bool OUT_F16, bool HAS_BIAS>
__global__ __launch_bounds__(256, 2) void gemm_mfma(
    const _Float16* __restrict__ A,
    const _Float16* __restrict__ BT,
    const float* __restrict__ bias,
    void* __restrict__ Cout,
    int Nn, int K)
{
  __shared__ _Float16 As[128 * 32];
  __shared__ _Float16 Bs[128 * 32];

  const int t  = threadIdx.x;
  const int bn = blockIdx.x * 128;
  const int bm = blockIdx.y * 128;
  const int l  = t & 63, wv = t >> 6;
  const int wr = wv >> 1, wc = wv & 1;

  f32x4 acc[4][4] = {};

  const int arow = t >> 2;            // 0..63
  const int ac   = (t & 3) * 8;       // k chunk start (halfs)

  for (int k0 = 0; k0 < K; k0 += 32) {
    __syncthreads();
    gload16(A  + (size_t)(bm + arow)      * K + k0 + ac, &As[t * 8]);
    gload16(A  + (size_t)(bm + 64 + arow) * K + k0 + ac, &As[2048 + t * 8]);
    gload16(BT + (size_t)(bn + arow)      * K + k0 + ac, &Bs[t * 8]);
    gload16(BT + (size_t)(bn + 64 + arow) * K + k0 + ac, &Bs[2048 + t * 8]);
    __syncthreads();

    const int rA = l & 15, ks = (l >> 4) * 8;
    f16x8 aF[4], bF[4];
#pragma unroll
    for (int i = 0; i < 4; ++i)
      aF[i] = *(const f16x8*)&As[(wr * 64 + i * 16 + rA) * 32 + ks];
#pragma unroll
    for (int j = 0; j < 4; ++j)
      bF[j] = *(const f16x8*)&Bs[(wc * 64 + j * 16 + rA) * 32 + ks];
#pragma unroll
    for (int i = 0; i < 4; ++i)
#pragma unroll
      for (int j = 0; j < 4; ++j)
        acc[i][j] = __builtin_amdgcn_mfma_f32_16x16x32_f16(aF[i], bF[j], acc[i][j], 0, 0, 0);
  }

  const int lc = l & 15, lr4 = (l >> 4) * 4;
#pragma unroll
  for (int i = 0; i < 4; ++i) {
    const int row0 = bm + wr * 64 + i * 16 + lr4;
#pragma unroll
    for (int j = 0; j < 4; ++j) {
      const int col = bn + wc * 64 + j * 16 + lc;
      const float bv = HAS_BIAS ? bias[col] : 0.f;
#pragma unroll
      for (int r = 0; r < 4; ++r) {
        const float v = acc[i][j][r] + bv;
        if (OUT_F16)
          ((_Float16*)Cout)[(size_t)(row0 + r) * Nn + col] = (_Float16)v;
        else
          ((float*)Cout)[(size_t)(row0 + r) * Nn + col] = v;
      }
    }
  }
}

// ---------------------------------------------------------------------------
// MFMA local attention. Block = (h, head, b), 512 thr = 8 waves; wave w owns
// query w-tile [w*16, w*16+16). Per key row kr in [h-3,h+3] clipped:
//   stage K row [128][64] f16 (chunk-swizzled, global_load_lds w/ pre-swizzled
//   source) + V row transposed to [64][128] (reg transpose, chunk ^ (d&15)).
//   QK^T: 4 mfma 16x16x32 (2 key tiles at kb=clamp(w0-8,0,96), 2 k-steps),
//   mask |kcol-w|<=5 on fp32 accs, online softmax per C-row (16-lane shfl),
//   P -> f16 -> per-wave LDS (swizzled) -> A-fragment; PV: 4 mfma, alpha-
//   rescaled fp32 accumulators. Epilogue: x 1/s, scalar f16 stores.
// ---------------------------------------------------------------------------
__global__ __launch_bounds__(512, 4) void local_attn_mfma(
    const _Float16* __restrict__ qkv, _Float16* __restrict__ outh)
{
  const int h = blockIdx.x, head = blockIdx.y, b = blockIdx.z;
  const int t = threadIdx.x;
  const int wave = t >> 6, l = t & 63;
  const int g = l >> 4, c = l & 15;
  const int w0 = wave * 16;
  const int kb = min(max(w0 - 8, 0), 96);     // 8-aligned key tile base

  __shared__ _Float16 Ksh[8192];              // [col][8 chunks of 8 halfs], swz
  __shared__ _Float16 Vsh[8192];              // [d][16 chunks of 8 halfs], swz
  __shared__ _Float16 Pbuf[8 * 512];          // per-wave 16x32 P, swz

  const _Float16* qb = qkv + (size_t)b * NN * ROWS;

  // ---- Q fragments (A-frag: row=c, k = s*32 + g*8 .. +7) ----
  f16x8 qF[2];
  {
    const _Float16* Qg = qb + (size_t)(h * Ww + w0 + c) * ROWS + head * HD;
#pragma unroll
    for (int s = 0; s < 2; ++s)
      qF[s] = *(const f16x8*)&Qg[s * 32 + g * 8];
  }

  const int r0 = max(0, h - 3), r1 = min(Hh - 1, h + 3);
  float m_run[4], s_run[4];
  f32x4 accO[4] = {};
#pragma unroll
  for (int r = 0; r < 4; ++r) { m_run[r] = -1e30f; s_run[r] = 0.f; }

  for (int kr = r0; kr <= r1; ++kr) {
    __syncthreads();                         // prior-iter readers done
    if (t < 256) {
      // ---- K: 1024 x 16B chunks, linear LDS dest, swizzled global source
      const _Float16* Kg = qb + (size_t)(kr * Ww) * ROWS + Cc + head * HD;
#pragma unroll
      for (int i = 0; i < 4; ++i) {
        const int o   = (i * 4 + wave) * 64 + l;     // linear chunk 0..1023
        const int col = o >> 3, dc = o & 7;
        gload16(Kg + (size_t)col * ROWS + ((dc ^ (col & 7)) << 3), &Ksh[o * 8]);
      }
    } else {
      // ---- V: transpose 4 cols x 8 d per thread, ds_write_b64
      const int j  = t - 256;
      const int dd = j & 7, cg = j >> 3;             // d-chunk, col-group
      const _Float16* Vg = qb + (size_t)(kr * Ww + cg * 4) * ROWS + 2 * Cc + head * HD + dd * 8;
      f16x8 vr[4];
#pragma unroll
      for (int i = 0; i < 4; ++i)
        vr[i] = *(const f16x8*)&Vg[(size_t)i * ROWS];
#pragma unroll
      for (int e = 0; e < 8; ++e) {
        const int d = dd * 8 + e;
        union { _Float16 hh[4]; uint2 u; } pk;
        pk.hh[0] = vr[0][e]; pk.hh[1] = vr[1][e];
        pk.hh[2] = vr[2][e]; pk.hh[3] = vr[3][e];
        const int hidx = d * 128 + (((cg >> 1) ^ (d & 15)) << 3) + (cg & 1) * 4;
        *(uint2*)&Vsh[hidx] = pk.u;
      }
    }
    __syncthreads();

    // ---- QK^T: S[q = g*4+r][kcol = kb + 16*tt + c] ----
    f32x4 accS[2] = {};
#pragma unroll
    for (int tt = 0; tt < 2; ++tt) {
      const int col = kb + 16 * tt + c;
#pragma unroll
      for (int s = 0; s < 2; ++s) {
        const f16x8 kF = *(const f16x8*)&Ksh[col * 64 + (((s * 4 + g) ^ (col & 7)) << 3)];
        accS[tt] = __builtin_amdgcn_mfma_f32_16x16x32_f16(qF[s], kF, accS[tt], 0, 0, 0);
      }
    }

    // ---- mask + online softmax (reduce across the 16-lane group) ----
    float alpha[4];
#pragma unroll
    for (int r = 0; r < 4; ++r) {
      const int w   = w0 + g * 4 + r;
      const int k0c = kb + c, k1c = kb + 16 + c;
      float s0 = (k0c >= w - 5 && k0c <= w + 5) ? accS[0][r] * SCALE : -1e30f;
      float s1 = (k1c >= w - 5 && k1c <= w + 5) ? accS[1][r] * SCALE : -1e30f;
      float mx = fmaxf(s0, s1);
#pragma unroll
      for (int msk = 1; msk < 16; msk <<= 1)
        mx = fmaxf(mx, __shfl_xor(mx, msk));
      const float mnew = fmaxf(m_run[r], mx);
      const float p0 = __expf(s0 - mnew);
      const float p1 = __expf(s1 - mnew);
      alpha[r] = __expf(m_run[r] - mnew);
      float ps = p0 + p1;
#pragma unroll
      for (int msk = 1; msk < 16; msk <<= 1)
        ps += __shfl_xor(ps, msk);
      s_run[r] = s_run[r] * alpha[r] + ps;
      m_run[r] = mnew;
      const int q = g * 4 + r;
      Pbuf[wave * 512 + ((q * 32 + c)      ^ ((q & 3) << 3))] = (_Float16)p0;
      Pbuf[wave * 512 + ((q * 32 + 16 + c) ^ ((q & 3) << 3))] = (_Float16)p1;
    }

    // wave-local: drain P writes before re-reading as A-fragment
    asm volatile("s_waitcnt lgkmcnt(0)" ::: "memory");

    // ---- PV: O[q][d=16j+c] += P(16x32) * V(32x64-window) ----
    const f16x8 pF = *(const f16x8*)&Pbuf[wave * 512 + ((c * 32 + g * 8) ^ ((c & 3) << 3))];
#pragma unroll
    for (int jj = 0; jj < 4; ++jj)
#pragma unroll
      for (int r = 0; r < 4; ++r) accO[jj][r] *= alpha[r];
#pragma unroll
    for (int jj = 0; jj < 4; ++jj) {
      const int d = 16 * jj + c;
      const f16x8 vF = *(const f16x8*)&Vsh[d * 128 + ((((kb >> 3) + g) ^ c) << 3)];
      accO[jj] = __builtin_amdgcn_mfma_f32_16x16x32_f16(pF, vF, accO[jj], 0, 0, 0);
    }
  }

  // ---- epilogue: normalize, store f16 ----
  _Float16* ob = outh + ((size_t)b * NN + h * Ww + w0) * Cc + head * HD;
#pragma unroll
  for (int r = 0; r < 4; ++r) {
    const float inv = 1.f / s_run[r];
    const int q = g * 4 + r;
#pragma unroll
    for (int jj = 0; jj < 4; ++jj)
      ob[(size_t)q * Cc + 16 * jj + c] = (_Float16)(accO[jj][r] * inv);
  }
}

// ---------------------------------------------------------------------------
extern "C" void kernel_launch(void* const* d_in, const int* in_sizes, int n_in,
                              void* d_out, int out_size, void* d_ws, size_t ws_size,
                              hipStream_t stream)
{
  const float* x      = (const float*)d_in[0];   // [32,1024,512]
  const float* w_qkv  = (const float*)d_in[1];   // [512,1536]
  const float* w_proj = (const float*)d_in[2];   // [512,512]
  const float* b_proj = (const float*)d_in[3];   // [512]
  float* out = (float*)d_out;

  const int M = Bsz * NN;                        // 32768
  char* ws = (char*)d_ws;
  _Float16* xh    = (_Float16*)ws;                              // 33.55 MB
  _Float16* qkvh  = (_Float16*)(ws + 33554432);                 // 100.66 MB
  _Float16* attnh = (_Float16*)(ws + 33554432 + 100663296);     // 33.55 MB
  _Float16* wqT   = (_Float16*)(ws + 167772160);                // 1.57 MB
  _Float16* wpT   = (_Float16*)(ws + 167772160 + 1572864);      // 0.52 MB

  // converts
  cvt_f32_f16<<<(M * Cc / 4 + 255) / 256, 256, 0, stream>>>(x, xh, M * Cc / 4);
  tcvt<<<(ROWS * Cc + 255) / 256, 256, 0, stream>>>(w_qkv, wqT, ROWS, Cc);
  tcvt<<<(Cc * Cc + 255) / 256, 256, 0, stream>>>(w_proj, wpT, Cc, Cc);

  // qkv = x @ w_qkv   (f16 out)
  gemm_mfma<true, false><<<dim3(ROWS / 128, M / 128), 256, 0, stream>>>(
      xh, wqT, nullptr, qkvh, ROWS, Cc);

  // local attention (MFMA) -> compact f16 [32768,512]
  local_attn_mfma<<<dim3(Hh, NHEAD, Bsz), 512, 0, stream>>>(qkvh, attnh);

  // out = attn @ w_proj + bias  (f32 out)
  gemm_mfma<false, true><<<dim3(Cc / 128, M / 128), 256, 0, stream>>>(
      attnh, wpT, b_proj, out, Cc, Cc);
}

// Round 4
// 217.403 us; speedup vs baseline: 4.9855x; 1.1010x over previous
//
#include <hip/hip_runtime.h>

#define Bsz   32
#define Hh    8
#define Ww    128
#define Cc    512
#define NHEAD 8
#define HD    64
#define NN    1024
#define SCALE 0.125f
#define ROWS  1536

typedef _Float16 f16x8 __attribute__((ext_vector_type(8)));
typedef float    f32x4 __attribute__((ext_vector_type(4)));

// ---------------------------------------------------------------------------
// async global->LDS, 16B per lane (linear dest = wave base + lane*16)
// ---------------------------------------------------------------------------
__device__ __forceinline__ void gload16(const _Float16* g, _Float16* l) {
#if __has_builtin(__builtin_amdgcn_global_load_lds)
  __builtin_amdgcn_global_load_lds(
      (const __attribute__((address_space(1))) unsigned int*)g,
      (__attribute__((address_space(3))) unsigned int*)l, 16, 0, 0);
#else
  *(uint4*)l = *(const uint4*)g;
#endif
}

// ---------------------------------------------------------------------------
// converts
// ---------------------------------------------------------------------------
__global__ __launch_bounds__(256) void cvt_f32_f16(
    const float* __restrict__ in, _Float16* __restrict__ out, int n4) {
  const int i = blockIdx.x * 256 + threadIdx.x;
  if (i < n4) {
    const float4 v = *reinterpret_cast<const float4*>(&in[(size_t)i * 4]);
    _Float16 h[4] = {(_Float16)v.x, (_Float16)v.y, (_Float16)v.z, (_Float16)v.w};
    *reinterpret_cast<uint2*>(&out[(size_t)i * 4]) = *reinterpret_cast<uint2*>(h);
  }
}

// out[n*K + k] = in[k*Nn + n]  (f32 -> f16 transpose)
__global__ __launch_bounds__(256) void tcvt(
    const float* __restrict__ in, _Float16* __restrict__ out, int Nn, int K) {
  const int id = blockIdx.x * 256 + threadIdx.x;
  if (id < Nn * K) {
    const int n = id / K, k = id - n * K;
    out[id] = (_Float16)in[(size_t)k * Nn + n];
  }
}

// ---------------------------------------------------------------------------
// MFMA GEMM: C[M,Nn] = A[M,K](f16) * BT[Nn,K]^T(f16)  (+bias), 128x128 tile,
// BK=32, 4 waves, 4x4 fragments of mfma_f32_16x16x32_f16 per wave.
// ---------------------------------------------------------------------------
template<bool OUT_F16, bool HAS_BIAS>
__global__ __launch_bounds__(256, 2) void gemm_mfma(
    const _Float16* __restrict__ A,
    const _Float16* __restrict__ BT,
    const float* __restrict__ bias,
    void* __restrict__ Cout,
    int Nn, int K)
{
  __shared__ _Float16 As[128 * 32];
  __shared__ _Float16 Bs[128 * 32];

  const int t  = threadIdx.x;
  const int bn = blockIdx.x * 128;
  const int bm = blockIdx.y * 128;
  const int l  = t & 63, wv = t >> 6;
  const int wr = wv >> 1, wc = wv & 1;

  f32x4 acc[4][4] = {};

  const int arow = t >> 2;            // 0..63
  const int ac   = (t & 3) * 8;       // k chunk start (halfs)

  for (int k0 = 0; k0 < K; k0 += 32) {
    __syncthreads();
    gload16(A  + (size_t)(bm + arow)      * K + k0 + ac, &As[t * 8]);
    gload16(A  + (size_t)(bm + 64 + arow) * K + k0 + ac, &As[2048 + t * 8]);
    gload16(BT + (size_t)(bn + arow)      * K + k0 + ac, &Bs[t * 8]);
    gload16(BT + (size_t)(bn + 64 + arow) * K + k0 + ac, &Bs[2048 + t * 8]);
    __syncthreads();

    const int rA = l & 15, ks = (l >> 4) * 8;
    f16x8 aF[4], bF[4];
#pragma unroll
    for (int i = 0; i < 4; ++i)
      aF[i] = *(const f16x8*)&As[(wr * 64 + i * 16 + rA) * 32 + ks];
#pragma unroll
    for (int j = 0; j < 4; ++j)
      bF[j] = *(const f16x8*)&Bs[(wc * 64 + j * 16 + rA) * 32 + ks];
#pragma unroll
    for (int i = 0; i < 4; ++i)
#pragma unroll
      for (int j = 0; j < 4; ++j)
        acc[i][j] = __builtin_amdgcn_mfma_f32_16x16x32_f16(aF[i], bF[j], acc[i][j], 0, 0, 0);
  }

  const int lc = l & 15, lr4 = (l >> 4) * 4;
#pragma unroll
  for (int i = 0; i < 4; ++i) {
    const int row0 = bm + wr * 64 + i * 16 + lr4;
#pragma unroll
    for (int j = 0; j < 4; ++j) {
      const int col = bn + wc * 64 + j * 16 + lc;
      const float bv = HAS_BIAS ? bias[col] : 0.f;
#pragma unroll
      for (int r = 0; r < 4; ++r) {
        const float v = acc[i][j][r] + bv;
        if (OUT_F16)
          ((_Float16*)Cout)[(size_t)(row0 + r) * Nn + col] = (_Float16)v;
        else
          ((float*)Cout)[(size_t)(row0 + r) * Nn + col] = v;
      }
    }
  }
}

// ---------------------------------------------------------------------------
// MFMA local attention, h-paired + XCD-chunked swizzle.
// Block = (h-pair, head, b) remapped so each XCD's chunk of 128 blocks shares
// (b,head) K/V slices -> L2 reuse. 512 thr = 8 waves; wave owns query w-tile
// [w*16,w*16+16) for BOTH rows h0,h0+1. Per key row kr in [h0-3,h0+4] clip:
// stage K row (swizzled chunks via gload_lds) + V row transposed; then for
// each in-window h: QK^T (4 mfma), mask, online softmax (16-lane shfl),
// P->f16->LDS->A-frag, PV (4 mfma). Sync structure identical to round 3.
// ---------------------------------------------------------------------------
__global__ __launch_bounds__(512, 4) void local_attn_mfma(
    const _Float16* __restrict__ qkv, _Float16* __restrict__ outh)
{
  // 1024 workgroups; chunk of 128 consecutive work-ids per XCD (bijective:
  // nwg % 8 == 0). Dispatch id wg lands on XCD wg&7 (round-robin).
  const int wg  = blockIdx.x + (Hh / 2) * (blockIdx.y + NHEAD * blockIdx.z);
  const int nid = ((wg & 7) << 7) + (wg >> 3);
  const int hp = nid & 3, head = (nid >> 2) & 7, b = nid >> 5;
  const int h0 = hp * 2;

  const int t = threadIdx.x;
  const int wave = t >> 6, l = t & 63;
  const int g = l >> 4, c = l & 15;
  const int w0 = wave * 16;
  const int kb = min(max(w0 - 8, 0), 96);     // 8-aligned key tile base

  __shared__ _Float16 Ksh[8192];              // [col][8 chunks of 8 halfs], swz
  __shared__ _Float16 Vsh[8192];              // [d][16 chunks of 8 halfs], swz
  __shared__ _Float16 Pbuf[8 * 512];          // per-wave 16x32 P, swz

  const _Float16* qb = qkv + (size_t)b * NN * ROWS;

  // ---- Q fragments for both h rows (A-frag: row=c, k = s*32 + g*8 .. +7) ----
  f16x8 qF[2][2];
#pragma unroll
  for (int hi = 0; hi < 2; ++hi) {
    const _Float16* Qg = qb + (size_t)((h0 + hi) * Ww + w0 + c) * ROWS + head * HD;
    qF[hi][0] = *(const f16x8*)&Qg[g * 8];
    qF[hi][1] = *(const f16x8*)&Qg[32 + g * 8];
  }

  // h-independent column masks (per accumulator row r)
  bool cm0[4], cm1[4];
#pragma unroll
  for (int r = 0; r < 4; ++r) {
    const int w = w0 + g * 4 + r;
    cm0[r] = (kb + c      >= w - 5) && (kb + c      <= w + 5);
    cm1[r] = (kb + 16 + c >= w - 5) && (kb + 16 + c <= w + 5);
  }

  const int r0 = max(0, h0 - 3), r1 = min(Hh - 1, h0 + 4);
  float m_run[2][4], s_run[2][4];
  f32x4 accO[2][4] = {};
#pragma unroll
  for (int hi = 0; hi < 2; ++hi)
#pragma unroll
    for (int r = 0; r < 4; ++r) { m_run[hi][r] = -1e30f; s_run[hi][r] = 0.f; }

  for (int kr = r0; kr <= r1; ++kr) {
    __syncthreads();                         // prior-iter readers done
    if (t < 256) {
      // ---- K: 1024 x 16B chunks, linear LDS dest, swizzled global source
      const _Float16* Kg = qb + (size_t)(kr * Ww) * ROWS + Cc + head * HD;
#pragma unroll
      for (int i = 0; i < 4; ++i) {
        const int o   = (i * 4 + wave) * 64 + l;     // linear chunk 0..1023
        const int col = o >> 3, dc = o & 7;
        gload16(Kg + (size_t)col * ROWS + ((dc ^ (col & 7)) << 3), &Ksh[o * 8]);
      }
    } else {
      // ---- V: transpose 4 cols x 8 d per thread, ds_write_b64
      const int j  = t - 256;
      const int dd = j & 7, cg = j >> 3;             // d-chunk, col-group
      const _Float16* Vg = qb + (size_t)(kr * Ww + cg * 4) * ROWS + 2 * Cc + head * HD + dd * 8;
      f16x8 vr[4];
#pragma unroll
      for (int i = 0; i < 4; ++i)
        vr[i] = *(const f16x8*)&Vg[(size_t)i * ROWS];
#pragma unroll
      for (int e = 0; e < 8; ++e) {
        const int d = dd * 8 + e;
        union { _Float16 hh[4]; uint2 u; } pk;
        pk.hh[0] = vr[0][e]; pk.hh[1] = vr[1][e];
        pk.hh[2] = vr[2][e]; pk.hh[3] = vr[3][e];
        const int hidx = d * 128 + (((cg >> 1) ^ (d & 15)) << 3) + (cg & 1) * 4;
        *(uint2*)&Vsh[hidx] = pk.u;
      }
    }
    __syncthreads();

#pragma unroll
    for (int hi = 0; hi < 2; ++hi) {
      const int hq = h0 + hi;
      if (kr < hq - 3 || kr > hq + 3) continue;   // row outside this h's window

      // ---- QK^T: S[q = g*4+r][kcol = kb + 16*tt + c] ----
      f32x4 accS[2] = {};
#pragma unroll
      for (int tt = 0; tt < 2; ++tt) {
        const int col = kb + 16 * tt + c;
#pragma unroll
        for (int s = 0; s < 2; ++s) {
          const f16x8 kF = *(const f16x8*)&Ksh[col * 64 + (((s * 4 + g) ^ (col & 7)) << 3)];
          accS[tt] = __builtin_amdgcn_mfma_f32_16x16x32_f16(qF[hi][s], kF, accS[tt], 0, 0, 0);
        }
      }

      // ---- mask + online softmax (reduce across the 16-lane group) ----
      float alpha[4];
#pragma unroll
      for (int r = 0; r < 4; ++r) {
        float s0 = cm0[r] ? accS[0][r] * SCALE : -1e30f;
        float s1 = cm1[r] ? accS[1][r] * SCALE : -1e30f;
        float mx = fmaxf(s0, s1);
#pragma unroll
        for (int msk = 1; msk < 16; msk <<= 1)
          mx = fmaxf(mx, __shfl_xor(mx, msk));
        const float mnew = fmaxf(m_run[hi][r], mx);
        const float p0 = __expf(s0 - mnew);
        const float p1 = __expf(s1 - mnew);
        alpha[r] = __expf(m_run[hi][r] - mnew);
        float ps = p0 + p1;
#pragma unroll
        for (int msk = 1; msk < 16; msk <<= 1)
          ps += __shfl_xor(ps, msk);
        s_run[hi][r] = s_run[hi][r] * alpha[r] + ps;
        m_run[hi][r] = mnew;
        const int q = g * 4 + r;
        Pbuf[wave * 512 + ((q * 32 + c)      ^ ((q & 3) << 3))] = (_Float16)p0;
        Pbuf[wave * 512 + ((q * 32 + 16 + c) ^ ((q & 3) << 3))] = (_Float16)p1;
      }

      // wave-local: drain P writes before re-reading as A-fragment
      asm volatile("s_waitcnt lgkmcnt(0)" ::: "memory");

      // ---- PV: O[q][d=16j+c] += P(16x32) * V(32x64-window) ----
      const f16x8 pF = *(const f16x8*)&Pbuf[wave * 512 + ((c * 32 + g * 8) ^ ((c & 3) << 3))];
#pragma unroll
      for (int jj = 0; jj < 4; ++jj)
#pragma unroll
        for (int r = 0; r < 4; ++r) accO[hi][jj][r] *= alpha[r];
#pragma unroll
      for (int jj = 0; jj < 4; ++jj) {
        const int d = 16 * jj + c;
        const f16x8 vF = *(const f16x8*)&Vsh[d * 128 + ((((kb >> 3) + g) ^ c) << 3)];
        accO[hi][jj] = __builtin_amdgcn_mfma_f32_16x16x32_f16(pF, vF, accO[hi][jj], 0, 0, 0);
      }
    }
  }

  // ---- epilogue: normalize, store f16 for both h rows ----
#pragma unroll
  for (int hi = 0; hi < 2; ++hi) {
    _Float16* ob = outh + ((size_t)b * NN + (h0 + hi) * Ww + w0) * Cc + head * HD;
#pragma unroll
    for (int r = 0; r < 4; ++r) {
      const float inv = 1.f / s_run[hi][r];
      const int q = g * 4 + r;
#pragma unroll
      for (int jj = 0; jj < 4; ++jj)
        ob[(size_t)q * Cc + 16 * jj + c] = (_Float16)(accO[hi][jj][r] * inv);
    }
  }
}

// ---------------------------------------------------------------------------
extern "C" void kernel_launch(void* const* d_in, const int* in_sizes, int n_in,
                              void* d_out, int out_size, void* d_ws, size_t ws_size,
                              hipStream_t stream)
{
  const float* x      = (const float*)d_in[0];   // [32,1024,512]
  const float* w_qkv  = (const float*)d_in[1];   // [512,1536]
  const float* w_proj = (const float*)d_in[2];   // [512,512]
  const float* b_proj = (const float*)d_in[3];   // [512]
  float* out = (float*)d_out;

  const int M = Bsz * NN;                        // 32768
  char* ws = (char*)d_ws;
  _Float16* xh    = (_Float16*)ws;                              // 33.55 MB
  _Float16* qkvh  = (_Float16*)(ws + 33554432);                 // 100.66 MB
  _Float16* attnh = (_Float16*)(ws + 33554432 + 100663296);     // 33.55 MB
  _Float16* wqT   = (_Float16*)(ws + 167772160);                // 1.57 MB
  _Float16* wpT   = (_Float16*)(ws + 167772160 + 1572864);      // 0.52 MB

  // converts
  cvt_f32_f16<<<(M * Cc / 4 + 255) / 256, 256, 0, stream>>>(x, xh, M * Cc / 4);
  tcvt<<<(ROWS * Cc + 255) / 256, 256, 0, stream>>>(w_qkv, wqT, ROWS, Cc);
  tcvt<<<(Cc * Cc + 255) / 256, 256, 0, stream>>>(w_proj, wpT, Cc, Cc);

  // qkv = x @ w_qkv   (f16 out)
  gemm_mfma<true, false><<<dim3(ROWS / 128, M / 128), 256, 0, stream>>>(
      xh, wqT, nullptr, qkvh, ROWS, Cc);

  // local attention (MFMA, h-paired) -> compact f16 [32768,512]
  local_attn_mfma<<<dim3(Hh / 2, NHEAD, Bsz), 512, 0, stream>>>(qkvh, attnh);

  // out = attn @ w_proj + bias  (f32 out)
  gemm_mfma<false, true><<<dim3(Cc / 128, M / 128), 256, 0, stream>>>(
      attnh, wpT, b_proj, out, Cc, Cc);
}